// Round 7
// baseline (199.239 us; speedup 1.0000x reference)
//
#include <hip/hip_runtime.h>
#include <math.h>

#define NB 8             // batch
#define NPIX 262144      // 512*512
#define NBINS1 1024      // level-1: top 10 float bits
#define NBINS2 2048      // level-2: bits 21..11
#define TPB 256
#define BPS 256          // pass1 blocks per sample -> 2048 blocks, 8/CU
#define PPB 1024         // pixels per block (4 per thread)
#define HBPU 128         // pass2 blocks per unit -> 2048 blocks, 8/CU
#define VPB 2048         // values per pass2 block (8 per thread, 2 float4 loads)
#define EPS2 1e-12f
#define NOTK 0xFFFFFFFFu

struct SelState { unsigned b1; unsigned rem; unsigned k; unsigned pad; };

#define F4E(v,j) (((const float*)&(v))[j])
#define I4E(v,j) (((const int*)&(v))[j])

__device__ __forceinline__ void pixel_vals(float a, float p,
                                           float i0, float i1, float i2,
                                           float f0, float f1, float f2,
                                           float g0, float g1, float g2,
                                           float& d, float& dc)
{
    float diff = a * (1.0f / 255.0f) - p;
    d = sqrtf(diff * diff + EPS2);
    float om = 1.0f - p;
    float e0 = i0 - (f0 * p + om * g0);
    float e1 = i1 - (f1 * p + om * g1);
    float e2 = i2 - (f2 * p + om * g2);
    dc = sqrtf(e0 * e0 + EPS2) + sqrtf(e1 * e1 + EPS2) + sqrtf(e2 * e2 + EPS2);
}

// ---------------- Pass 1: stream inputs -> vals + fused level-1 count hist (1024 bins) ----------------
__global__ __launch_bounds__(TPB) void k_pass1(
    const float* __restrict__ image, const float* __restrict__ alpha,
    const float* __restrict__ pred, const int* __restrict__ trimap,
    const float* __restrict__ fg, const float* __restrict__ bg,
    unsigned* __restrict__ gcnt, unsigned* __restrict__ h1c, float* __restrict__ vals)
{
    __shared__ unsigned hc[2 * NBINS1];   // 8 KB: [0..1024) d, [1024..2048) dc
    const int tid = threadIdx.x;
    for (int i = tid; i < 2 * NBINS1; i += TPB) hc[i] = 0u;
    __syncthreads();

    const int s = blockIdx.x >> 8;        // BPS == 256
    const int chunk = blockIdx.x & 255;
    const int pbase = s * NPIX + chunk * PPB;
    const int cbase = s * 3 * NPIX + chunk * PPB;
    float* vd = vals + (s * 2 + 0) * NPIX + chunk * PPB;
    float* vc = vals + (s * 2 + 1) * NPIX + chunk * PPB;

    const float md  = sqrtf(EPS2);        // masked d value (also min possible d)
    const float mdc = md + md + md;
    const unsigned mdbits  = __float_as_uint(md);
    const unsigned mdcbits = __float_as_uint(mdc);

    const int off = tid * 4;
    int4   tm = *(const int4*)(trimap + pbase + off);
    float4 al = *(const float4*)(alpha + pbase + off);
    float4 pr = *(const float4*)(pred + pbase + off);
    float4 i0 = *(const float4*)(image + cbase + off);
    float4 i1 = *(const float4*)(image + cbase + NPIX + off);
    float4 i2 = *(const float4*)(image + cbase + 2 * NPIX + off);
    float4 f0 = *(const float4*)(fg + cbase + off);
    float4 f1 = *(const float4*)(fg + cbase + NPIX + off);
    float4 f2 = *(const float4*)(fg + cbase + 2 * NPIX + off);
    float4 g0 = *(const float4*)(bg + cbase + off);
    float4 g1 = *(const float4*)(bg + cbase + NPIX + off);
    float4 g2 = *(const float4*)(bg + cbase + 2 * NPIX + off);

    unsigned nUnk = 0, mD = 0, mC = 0;    // masked/min-constant aggregates
    float4 od, oc;
#pragma unroll
    for (int j = 0; j < 4; ++j) {
        float d, dc;
        if (I4E(tm, j) == 128) {
            ++nUnk;
            pixel_vals(F4E(al, j), F4E(pr, j),
                       F4E(i0, j), F4E(i1, j), F4E(i2, j),
                       F4E(f0, j), F4E(f1, j), F4E(f2, j),
                       F4E(g0, j), F4E(g1, j), F4E(g2, j), d, dc);
        } else {
            d = md; dc = mdc;
        }
        unsigned db = __float_as_uint(d), cb = __float_as_uint(dc);
        if (db == mdbits) ++mD; else atomicAdd(&hc[db >> 22], 1u);
        if (cb == mdcbits) ++mC; else atomicAdd(&hc[NBINS1 + (cb >> 22)], 1u);
        ((float*)&od)[j] = d;
        ((float*)&oc)[j] = dc;
    }
    *(float4*)(vd + off) = od;
    *(float4*)(vc + off) = oc;

    unsigned u = nUnk, a = mD, b = mC;
#pragma unroll
    for (int o = 32; o > 0; o >>= 1) {
        u += __shfl_down(u, o); a += __shfl_down(a, o); b += __shfl_down(b, o);
    }
    __shared__ unsigned wred[4];
    if ((tid & 63) == 0) {
        if (a) atomicAdd(&hc[mdbits >> 22], a);
        if (b) atomicAdd(&hc[NBINS1 + (mdcbits >> 22)], b);
        wred[tid >> 6] = u;
    }
    __syncthreads();
    if (tid == 0) atomicAdd(&gcnt[s], wred[0] + wred[1] + wred[2] + wred[3]);

    for (int i = tid; i < 2 * NBINS1; i += TPB) {
        unsigned c = hc[i];
        if (c) atomicAdd(&h1c[((s << 1) + (i >= NBINS1 ? 1 : 0)) * NBINS1 + (i & (NBINS1 - 1))], c);
    }
}

// ---------------- select1 (16 blocks): find b1; also zero h2/sumgt/out ----------------
__global__ __launch_bounds__(TPB) void k_select1(
    const unsigned* __restrict__ gcnt, const unsigned* __restrict__ h1c,
    SelState* __restrict__ st, unsigned* __restrict__ h2c, float* __restrict__ h2s,
    float* __restrict__ sumgt, float* __restrict__ out)
{
    const int unit = blockIdx.x;
    const int t = threadIdx.x;

    // zero this unit's level-2 rows + (block 0) sumgt/out — consumed only after this kernel
    for (int i = t; i < NBINS2; i += TPB) { h2c[unit * NBINS2 + i] = 0u; h2s[unit * NBINS2 + i] = 0.f; }
    if (unit == 0) {
        if (t < 16) sumgt[t] = 0.f;
        if (t == 0) out[0] = 0.f;
    }

    const unsigned* hc = h1c + unit * NBINS1;
    unsigned count = gcnt[unit >> 1];
    int k = (int)floorf((float)count * 0.7f);

    __shared__ unsigned spc[TPB];
    unsigned pc = 0;
#pragma unroll
    for (int j = 0; j < NBINS1 / TPB; ++j) pc += hc[t * (NBINS1 / TPB) + j];
    spc[t] = pc;
    __syncthreads();
    __shared__ unsigned sufc[TPB + 1];
    if (t == 0) {
        unsigned c = 0; sufc[TPB] = 0;
        for (int i = TPB - 1; i >= 0; --i) { c += spc[i]; sufc[i] = c; }
    }
    __syncthreads();
    if (k <= 0) {
        if (t == 0) { st[unit].b1 = NOTK; st[unit].rem = 0; st[unit].k = 0; }
        return;
    }
    unsigned above = sufc[t + 1];
    if (above < (unsigned)k && (unsigned)k <= sufc[t]) {
        unsigned c = above;
        int b1 = t * (NBINS1 / TPB);
        for (int j = NBINS1 / TPB - 1; j >= 0; --j) {
            unsigned bcn = hc[t * (NBINS1 / TPB) + j];
            if (c + bcn >= (unsigned)k) { b1 = t * (NBINS1 / TPB) + j; break; }
            c += bcn;
        }
        st[unit].b1 = (unsigned)b1;
        st[unit].rem = (unsigned)k - c;   // >= 1
        st[unit].k = (unsigned)k;
    }
}

// ---------------- Pass 2: sum above b1; level-2 hist (bits 21..11) for bin == b1 ----------------
__global__ __launch_bounds__(TPB) void k_pass2(
    const float* __restrict__ vals, const SelState* __restrict__ st,
    unsigned* __restrict__ h2c, float* __restrict__ h2s, float* __restrict__ sumgt)
{
    const int unit = blockIdx.x >> 7;     // HBPU == 128
    const int chunk = blockIdx.x & 127;
    const SelState S = st[unit];
    if (S.b1 == NOTK) return;
    const float* v = vals + unit * NPIX + chunk * VPB;
    unsigned* hcd = h2c + unit * NBINS2;
    float*    hsd = h2s + unit * NBINS2;
    const int tid = threadIdx.x;

    const float md = sqrtf(EPS2);
    const float mconst = (unit & 1) ? (md + md + md) : md;
    const unsigned mbits = __float_as_uint(mconst);
    const bool magg = (mbits >> 22) == S.b1;   // masked constant lands in boundary bin?

    // issue both loads back-to-back -> 2 outstanding vmem ops per wave
    const int off = tid * 4;
    float4 x0 = *(const float4*)(v + off);
    float4 x1 = *(const float4*)(v + TPB * 4 + off);

    float lsum = 0.f;
    unsigned mloc = 0;
#pragma unroll
    for (int h = 0; h < 2; ++h) {
        float4 x = h ? x1 : x0;
#pragma unroll
        for (int j = 0; j < 4; ++j) {
            float val = F4E(x, j);
            unsigned bits = __float_as_uint(val);
            unsigned b = bits >> 22;
            if (b > S.b1) {
                lsum += val;
            } else if (b == S.b1) {
                if (bits == mbits) { ++mloc; }   // identical values -> aggregate
                else {
                    unsigned sb = (bits >> 11) & (NBINS2 - 1);
                    atomicAdd(&hcd[sb], 1u);
                    atomicAdd(&hsd[sb], val);
                }
            }
        }
    }
#pragma unroll
    for (int o = 32; o > 0; o >>= 1) { lsum += __shfl_down(lsum, o); mloc += __shfl_down(mloc, o); }
    __shared__ float wred[4];
    if ((tid & 63) == 0) {
        wred[tid >> 6] = lsum;
        if (magg && mloc) {
            unsigned sb = (mbits >> 11) & (NBINS2 - 1);
            atomicAdd(&hcd[sb], mloc);
            atomicAdd(&hsd[sb], (float)mloc * mconst);
        }
    }
    __syncthreads();
    if (tid == 0) atomicAdd(&sumgt[unit], wred[0] + wred[1] + wred[2] + wred[3]);
}

// ---------------- select2 + final combine ----------------
__global__ __launch_bounds__(TPB) void k_select2_final(
    const unsigned* __restrict__ h2c, const float* __restrict__ h2s,
    const SelState* __restrict__ st, const float* __restrict__ sumgt,
    float* __restrict__ out)
{
    const int unit = blockIdx.x;
    const int t = threadIdx.x;
    SelState S = st[unit];
    if (S.b1 == NOTK) return;   // k==0 contributes 0
    const unsigned* hc = h2c + unit * NBINS2;
    const float*    hm = h2s + unit * NBINS2;

    __shared__ unsigned spc[TPB]; __shared__ float sps[TPB];
    unsigned pc = 0; float ps = 0.f;
#pragma unroll
    for (int j = 0; j < NBINS2 / TPB; ++j) { pc += hc[t * (NBINS2 / TPB) + j]; ps += hm[t * (NBINS2 / TPB) + j]; }
    spc[t] = pc; sps[t] = ps;
    __syncthreads();
    __shared__ unsigned sufc[TPB + 1]; __shared__ float sufs[TPB + 1];
    if (t == 0) {
        unsigned c = 0; float sm = 0.f;
        sufc[TPB] = 0; sufs[TPB] = 0.f;
        for (int i = TPB - 1; i >= 0; --i) { c += spc[i]; sm += sps[i]; sufc[i] = c; sufs[i] = sm; }
    }
    __syncthreads();
    unsigned k = S.rem;                 // >= 1, crossing guaranteed
    unsigned above = sufc[t + 1];
    if (above < k && k <= sufc[t]) {
        unsigned c = above; float sm = sufs[t + 1];
        unsigned bcn = 0; float bsm = 0.f;
        for (int j = NBINS2 / TPB - 1; j >= 0; --j) {
            bcn = hc[t * (NBINS2 / TPB) + j]; bsm = hm[t * (NBINS2 / TPB) + j];
            if (c + bcn >= k) break;
            c += bcn; sm += bsm;
        }
        unsigned rem2 = k - c;
        float avg = bsm / (float)bcn;   // 21 known bits -> ~2^-13 relative bin width
        float sum_k = sumgt[unit] + sm + (float)rem2 * avg;
        float loss = sum_k / ((float)S.k + 1e-6f);
        atomicAdd(out, 0.0625f * loss); // 0.5 stage weight / 8 samples, both arrays
    }
}

extern "C" void kernel_launch(void* const* d_in, const int* in_sizes, int n_in,
                              void* d_out, int out_size, void* d_ws, size_t ws_size,
                              hipStream_t stream)
{
    const float* image  = (const float*)d_in[0];
    const float* alpha  = (const float*)d_in[1];
    const float* pred   = (const float*)d_in[2];
    const int*   trimap = (const int*)d_in[3];
    const float* fg     = (const float*)d_in[4];
    const float* bg     = (const float*)d_in[5];
    float* out = (float*)d_out;

    char* ws = (char*)d_ws;
    // layout: gcnt(64B) | sumgt(64B) | h1c(64KB) | h2c(128KB) | h2s(128KB) | st(256B) | vals(16MB)
    unsigned* gcnt  = (unsigned*)(ws);
    float*    sumgt = (float*)(ws + 64);
    unsigned* h1c   = (unsigned*)(ws + 128);
    unsigned* h2c   = (unsigned*)(ws + 128 + 65536);
    float*    h2s   = (float*)(ws + 128 + 65536 + 131072);
    SelState* st    = (SelState*)(ws + 128 + 65536 + 2 * 131072);
    float*    vals  = (float*)(ws + 524288);

    // zero only what pass1 accumulates into (gcnt + h1c); rest zeroed inside select1
    hipMemsetAsync(d_ws, 0, 128 + 65536, stream);
    k_pass1<<<NB * BPS, TPB, 0, stream>>>(image, alpha, pred, trimap, fg, bg, gcnt, h1c, vals);
    k_select1<<<16, TPB, 0, stream>>>(gcnt, h1c, st, h2c, h2s, sumgt, out);
    k_pass2<<<16 * HBPU, TPB, 0, stream>>>(vals, st, h2c, h2s, sumgt);
    k_select2_final<<<16, TPB, 0, stream>>>(h2c, h2s, st, sumgt, out);
}